// Round 1
// baseline (695.357 us; speedup 1.0000x reference)
//
#include <hip/hip_runtime.h>

#define S_LEN 2048
#define D_DIM 128
#define BQ 128
#define BK 32
#define NITER (S_LEN / BK)   // 64

typedef float f32x4 __attribute__((ext_vector_type(4)));
typedef short s16x8 __attribute__((ext_vector_type(8)));
typedef unsigned short u16x4 __attribute__((ext_vector_type(4)));

// LDS row strides (in ushorts). Chosen so ds_read_b128 fragment reads are
// 16B-aligned and land at worst 2-way bank aliasing (free on wave64, m136).
#define KROW 264   // 16 chunks * 16 (hi8|lo8 interleaved) + 8 pad = 528 B/row
#define VROW 40    // 32 kk + 8 pad = 80 B/row (d-major, transposed V)
#define PROW 40    // 32 kk + 8 pad per P row

__device__ __forceinline__ unsigned short f2bf_rne(float x) {
    union { float f; unsigned u; } a; a.f = x;
    unsigned r = a.u + 0x7FFFu + ((a.u >> 16) & 1u);
    return (unsigned short)(r >> 16);
}

__global__ __launch_bounds__(256, 2)
void attn_fused(const float* __restrict__ Q, const float* __restrict__ K,
                const float* __restrict__ V, const float* __restrict__ SF,
                const int* __restrict__ DP, float* __restrict__ OUT)
{
    __shared__ __align__(16) unsigned short sK[BK * KROW];        // 16896 B
    __shared__ __align__(16) unsigned short sVt[D_DIM * VROW];    // 10240 B
    __shared__ __align__(16) unsigned short sP[4 * 32 * PROW];    // 10240 B

    const int bh   = blockIdx.y;
    const int q0   = blockIdx.x * BQ;
    const int tid  = threadIdx.x;
    const int w    = tid >> 6;
    const int lane = tid & 63;
    const int quad = lane >> 4;
    const int lr   = lane & 15;

    const size_t bh_off = (size_t)bh * S_LEN * D_DIM;
    const float LOG2E = 1.4426950408889634f;

    // ---- Q fragments, hi/lo bf16 split, kept in registers for the whole kernel ----
    // A-frag layout (16x16x32): lane holds A[m=lane&15][k = quad*8 + j], j=0..7
    s16x8 qhi[2][4], qlo[2][4];
    #pragma unroll
    for (int mt = 0; mt < 2; ++mt) {
        const int row = q0 + w * 32 + mt * 16 + lr;
        const float* qr = Q + bh_off + (size_t)row * D_DIM + quad * 8;
        #pragma unroll
        for (int d0 = 0; d0 < 4; ++d0) {
            const float4 u0 = *(const float4*)(qr + d0 * 32);
            const float4 u1 = *(const float4*)(qr + d0 * 32 + 4);
            float xs[8] = {u0.x,u0.y,u0.z,u0.w,u1.x,u1.y,u1.z,u1.w};
            union { s16x8 v; unsigned short u[8]; } H, L;
            #pragma unroll
            for (int j = 0; j < 8; ++j) {
                union { float f; unsigned u; } b; b.f = xs[j];
                const unsigned hb = b.u & 0xFFFF0000u;       // truncated bf16 hi
                H.u[j] = (unsigned short)(hb >> 16);
                union { unsigned u; float f; } hf; hf.u = hb;
                L.u[j] = f2bf_rne(xs[j] - hf.f);             // residual, RNE bf16
            }
            qhi[mt][d0] = H.v; qlo[mt][d0] = L.v;
        }
    }

    f32x4 Oacc[2][8] = {};
    float mrow[2][4], lrow[2][4];
    #pragma unroll
    for (int mt = 0; mt < 2; ++mt)
        #pragma unroll
        for (int r = 0; r < 4; ++r) { mrow[mt][r] = -INFINITY; lrow[mt][r] = 0.f; }

    for (int kt = 0; kt < NITER; ++kt) {
        const int k0 = kt * BK;
        __syncthreads();   // previous iteration's sK/sVt reads are done

        // ---- stage K tile: 32 rows x 128 d, hi|lo interleaved 8-elem chunks ----
        {
            const int r = tid >> 3, seg = tid & 7;
            const float* kr = K + bh_off + (size_t)(k0 + r) * D_DIM + seg * 16;
            unsigned short* dst = sK + r * KROW + seg * 32;
            float xs[16];
            const float4 a0 = *(const float4*)(kr + 0);
            const float4 a1 = *(const float4*)(kr + 4);
            const float4 a2 = *(const float4*)(kr + 8);
            const float4 a3 = *(const float4*)(kr + 12);
            xs[0]=a0.x; xs[1]=a0.y; xs[2]=a0.z; xs[3]=a0.w;
            xs[4]=a1.x; xs[5]=a1.y; xs[6]=a1.z; xs[7]=a1.w;
            xs[8]=a2.x; xs[9]=a2.y; xs[10]=a2.z; xs[11]=a2.w;
            xs[12]=a3.x; xs[13]=a3.y; xs[14]=a3.z; xs[15]=a3.w;
            union { s16x8 v; unsigned short u[8]; } h0, l0, h1, l1;
            #pragma unroll
            for (int j = 0; j < 8; ++j) {
                union { float f; unsigned u; } b; b.f = xs[j];
                const unsigned hb = b.u & 0xFFFF0000u;
                h0.u[j] = (unsigned short)(hb >> 16);
                union { unsigned u; float f; } hf; hf.u = hb;
                l0.u[j] = f2bf_rne(xs[j] - hf.f);
            }
            #pragma unroll
            for (int j = 0; j < 8; ++j) {
                union { float f; unsigned u; } b; b.f = xs[8+j];
                const unsigned hb = b.u & 0xFFFF0000u;
                h1.u[j] = (unsigned short)(hb >> 16);
                union { unsigned u; float f; } hf; hf.u = hb;
                l1.u[j] = f2bf_rne(xs[8+j] - hf.f);
            }
            *(s16x8*)(dst + 0)  = h0.v;
            *(s16x8*)(dst + 8)  = l0.v;
            *(s16x8*)(dst + 16) = h1.v;
            *(s16x8*)(dst + 24) = l1.v;
        }

        // ---- stage V tile transposed: sVt[d][kk] bf16 ----
        {
            const int c = tid & 127, half = tid >> 7;
            const float* vb = V + bh_off + (size_t)(k0 + half * 16) * D_DIM + c;
            unsigned short* dst = sVt + c * VROW + half * 16;
            #pragma unroll
            for (int rg = 0; rg < 4; ++rg) {
                u16x4 pk;
                pk[0] = f2bf_rne(vb[(rg*4+0) * D_DIM]);
                pk[1] = f2bf_rne(vb[(rg*4+1) * D_DIM]);
                pk[2] = f2bf_rne(vb[(rg*4+2) * D_DIM]);
                pk[3] = f2bf_rne(vb[(rg*4+3) * D_DIM]);
                *(u16x4*)(dst + rg * 4) = pk;
            }
        }

        __syncthreads();   // staging visible to all waves

        // ---- QK^T, hi/lo compensated (3 passes): S = qh*kh + qh*kl + ql*kh ----
        f32x4 acc[2][2] = {};
        #pragma unroll
        for (int nt = 0; nt < 2; ++nt) {
            #pragma unroll
            for (int d0 = 0; d0 < 4; ++d0) {
                const unsigned short* src = sK + (nt*16 + lr) * KROW + (d0*4 + quad) * 16;
                const s16x8 bh8 = *(const s16x8*)(src);
                const s16x8 bl8 = *(const s16x8*)(src + 8);
                #pragma unroll
                for (int mt = 0; mt < 2; ++mt) {
                    acc[mt][nt] = __builtin_amdgcn_mfma_f32_16x16x32_bf16(qlo[mt][d0], bh8, acc[mt][nt], 0, 0, 0);
                    acc[mt][nt] = __builtin_amdgcn_mfma_f32_16x16x32_bf16(qhi[mt][d0], bl8, acc[mt][nt], 0, 0, 0);
                    acc[mt][nt] = __builtin_amdgcn_mfma_f32_16x16x32_bf16(qhi[mt][d0], bh8, acc[mt][nt], 0, 0, 0);
                }
            }
        }

        // ---- per-element scale, online softmax (base-2) ----
        // C-layout: element r of acc[mt][nt] is (row = mt*16 + quad*4 + r, col = nt*16 + lr)
        unsigned short* pw = sP + w * (32 * PROW);   // per-wave-private region
        #pragma unroll
        for (int mt = 0; mt < 2; ++mt) {
            const int rbase = q0 + w * 32 + mt * 16 + quad * 4;
            float t0[4], t1[4];
            #pragma unroll
            for (int r = 0; r < 4; ++r) {
                const float sc0 = SF[(size_t)(rbase + r) * S_LEN + k0 + lr];
                const float sc1 = SF[(size_t)(rbase + r) * S_LEN + k0 + 16 + lr];
                t0[r] = acc[mt][0][r] * sc0 * LOG2E;
                t1[r] = acc[mt][1][r] * sc1 * LOG2E;
            }
            #pragma unroll
            for (int r = 0; r < 4; ++r) {
                float mx = fmaxf(t0[r], t1[r]);
                mx = fmaxf(mx, __shfl_xor(mx, 1));
                mx = fmaxf(mx, __shfl_xor(mx, 2));
                mx = fmaxf(mx, __shfl_xor(mx, 4));
                mx = fmaxf(mx, __shfl_xor(mx, 8));
                const float mnew = fmaxf(mrow[mt][r], mx);
                const float al = exp2f(mrow[mt][r] - mnew);  // first iter: exp2(-inf)=0
                mrow[mt][r] = mnew;
                const float p0 = exp2f(t0[r] - mnew);
                const float p1 = exp2f(t1[r] - mnew);
                float rs = p0 + p1;
                rs += __shfl_xor(rs, 1);
                rs += __shfl_xor(rs, 2);
                rs += __shfl_xor(rs, 4);
                rs += __shfl_xor(rs, 8);
                lrow[mt][r] = lrow[mt][r] * al + rs;
                #pragma unroll
                for (int dt = 0; dt < 8; ++dt)
                    Oacc[mt][dt][r] *= al;
                const int prow = mt * 16 + quad * 4 + r;
                pw[prow * PROW + lr]      = f2bf_rne(p0);
                pw[prow * PROW + 16 + lr] = f2bf_rne(p1);
            }
        }

        // ---- P·V (same-wave LDS round-trip: lgkmcnt dependency only, no barrier) ----
        s16x8 pa[2];
        pa[0] = *(const s16x8*)(pw + (0*16 + lr) * PROW + quad * 8);
        pa[1] = *(const s16x8*)(pw + (1*16 + lr) * PROW + quad * 8);
        #pragma unroll
        for (int dt = 0; dt < 8; ++dt) {
            const s16x8 bv = *(const s16x8*)(sVt + (dt*16 + lr) * VROW + quad * 8);
            Oacc[0][dt] = __builtin_amdgcn_mfma_f32_16x16x32_bf16(pa[0], bv, Oacc[0][dt], 0, 0, 0);
            Oacc[1][dt] = __builtin_amdgcn_mfma_f32_16x16x32_bf16(pa[1], bv, Oacc[1][dt], 0, 0, 0);
        }
    }

    // ---- epilogue: normalize by l, apply dropout_p scalar, fp32 store ----
    const float dpf = (float)DP[0];
    float* ob = OUT + bh_off + (size_t)(q0 + w * 32) * D_DIM;
    #pragma unroll
    for (int mt = 0; mt < 2; ++mt) {
        #pragma unroll
        for (int r = 0; r < 4; ++r) {
            const float sc = dpf / lrow[mt][r];
            const int row = mt * 16 + quad * 4 + r;
            #pragma unroll
            for (int dt = 0; dt < 8; ++dt)
                ob[(size_t)row * D_DIM + dt * 16 + lr] = Oacc[mt][dt][r] * sc;
        }
    }
}

extern "C" void kernel_launch(void* const* d_in, const int* in_sizes, int n_in,
                              void* d_out, int out_size, void* d_ws, size_t ws_size,
                              hipStream_t stream) {
    const float* q  = (const float*)d_in[0];
    const float* k  = (const float*)d_in[1];
    const float* v  = (const float*)d_in[2];
    const float* sf = (const float*)d_in[3];
    const int*   dp = (const int*)d_in[4];
    float* out = (float*)d_out;

    dim3 grid(S_LEN / BQ, 32);   // (16, 32) = 512 blocks, 2/CU
    dim3 block(256);
    attn_fused<<<grid, block, 0, stream>>>(q, k, v, sf, dp, out);
}

// Round 2
// 464.378 us; speedup vs baseline: 1.4974x; 1.4974x over previous
//
#include <hip/hip_runtime.h>

#define S_LEN 2048
#define D_DIM 128
#define BQ 64
#define BK 32
#define NITER (S_LEN / BK)   // 64

typedef float f32x4 __attribute__((ext_vector_type(4)));
typedef short s16x8 __attribute__((ext_vector_type(8)));
typedef unsigned short u16x4 __attribute__((ext_vector_type(4)));
typedef unsigned int u32;

#if __has_builtin(__builtin_amdgcn_exp2f)
#define EXP2(x) __builtin_amdgcn_exp2f(x)
#else
#define EXP2(x) exp2f(x)
#endif

// pack two floats' bf16 (truncated) into one u32: x1 in upper 16, x0 in lower
__device__ __forceinline__ u32 pack_trunc(float x0, float x1) {
    return __builtin_amdgcn_perm(__float_as_uint(x1), __float_as_uint(x0), 0x07060302u);
}
// round-to-nearest (half away) bf16 pack
__device__ __forceinline__ u32 pack_rne(float x0, float x1) {
    return __builtin_amdgcn_perm(__float_as_uint(x1) + 0x8000u,
                                 __float_as_uint(x0) + 0x8000u, 0x07060302u);
}

#define GLOAD16(g, l) \
    __builtin_amdgcn_global_load_lds((const __attribute__((address_space(1))) u32*)(g), \
                                     (__attribute__((address_space(3))) u32*)(l), 16, 0, 0)

// ---------------- pre-pass: K -> hi/lo bf16, tiled + XOR-swizzled 16B units ----------------
// Kc layout: [bh][kt][r=0..31][u'=0..31][8 ushorts], row = 512B = 32 units of 16B.
// logical unit u = 2c (hi of elems 8c..8c+7) / 2c+1 (lo); physical u' = u ^ (r&7).
__global__ void prep_k(const float* __restrict__ K, unsigned short* __restrict__ Kc) {
    const int t  = blockIdx.x * 256 + threadIdx.x;   // 2^20 threads
    const int c  = t & 15;
    const int s  = (t >> 4) & (S_LEN - 1);
    const int bh = t >> 15;
    const float* src = K + ((size_t)bh * S_LEN + s) * D_DIM + c * 8;
    const float4 a = *(const float4*)src;
    const float4 b = *(const float4*)(src + 4);
    const float x[8] = {a.x,a.y,a.z,a.w,b.x,b.y,b.z,b.w};
    u32 h[4], l[4];
    #pragma unroll
    for (int i = 0; i < 4; ++i) {
        const float x0 = x[2*i], x1 = x[2*i+1];
        h[i] = pack_trunc(x0, x1);
        const float r0 = x0 - __uint_as_float(__float_as_uint(x0) & 0xFFFF0000u);
        const float r1 = x1 - __uint_as_float(__float_as_uint(x1) & 0xFFFF0000u);
        l[i] = pack_trunc(r0, r1);
    }
    const int kt = s >> 5, r = s & 31, rl = r & 7;
    unsigned short* base = Kc + ((((size_t)bh * NITER + kt) * 32 + r) << 8);
    *(uint4*)(base + (((2*c)     ^ rl) << 3)) = make_uint4(h[0],h[1],h[2],h[3]);
    *(uint4*)(base + (((2*c + 1) ^ rl) << 3)) = make_uint4(l[0],l[1],l[2],l[3]);
}

// ---------------- pre-pass: V -> transposed bf16 tiles Vt[bh][kt][d][kk] ----------------
__global__ void prep_v(const float* __restrict__ V, unsigned short* __restrict__ Vt) {
    const int t  = blockIdx.x * 256 + threadIdx.x;   // 2^18 threads
    const int d  = t & 127;
    const int kt = (t >> 7) & (NITER - 1);
    const int bh = t >> 13;
    const float* src = V + (((size_t)bh * NITER + kt) * BK) * D_DIM + d;
    u32 wv[16];
    #pragma unroll
    for (int i = 0; i < 16; ++i)
        wv[i] = pack_rne(src[(2*i) * D_DIM], src[(2*i+1) * D_DIM]);
    unsigned short* dst = Vt + ((((size_t)bh * NITER + kt) * D_DIM + d) << 5);
    #pragma unroll
    for (int i = 0; i < 4; ++i)
        *(uint4*)(dst + i * 8) = make_uint4(wv[4*i],wv[4*i+1],wv[4*i+2],wv[4*i+3]);
}

// ---------------- hot kernel ----------------
__global__ __launch_bounds__(256, 4)
void attn_fused(const float* __restrict__ Q, const unsigned short* __restrict__ Kc,
                const unsigned short* __restrict__ Vt, const float* __restrict__ SF,
                const int* __restrict__ DP, float* __restrict__ OUT)
{
    __shared__ __align__(16) unsigned short sK[32 * 256];    // 16 KB
    __shared__ __align__(16) unsigned short sVt[128 * 32];   // 8 KB
    __shared__ __align__(16) unsigned short sP[4 * 16 * 40]; // 5 KB, wave-private regions

    const int bh   = blockIdx.y;
    const int q0   = blockIdx.x * BQ;
    const int tid  = threadIdx.x;
    const int w    = tid >> 6;
    const int lane = tid & 63;
    const int quad = lane >> 4;
    const int lr   = lane & 15;
    const int rl   = lr & 7;

    const size_t bh_off = (size_t)bh * S_LEN * D_DIM;
    const float LOG2E = 1.4426950408889634f;

    // ---- Q fragments, hi/lo bf16 split (A-frag: lane holds A[m=lr][k=quad*8+j]) ----
    s16x8 qhi[4], qlo[4];
    {
        const int qrow = q0 + w * 16 + lr;
        const float* qr = Q + bh_off + (size_t)qrow * D_DIM + quad * 8;
        #pragma unroll
        for (int d0 = 0; d0 < 4; ++d0) {
            const float4 u0 = *(const float4*)(qr + d0 * 32);
            const float4 u1 = *(const float4*)(qr + d0 * 32 + 4);
            const float x[8] = {u0.x,u0.y,u0.z,u0.w,u1.x,u1.y,u1.z,u1.w};
            union { u32 w4[4]; s16x8 v; } H, L;
            #pragma unroll
            for (int i = 0; i < 4; ++i) {
                const float x0 = x[2*i], x1 = x[2*i+1];
                H.w4[i] = pack_trunc(x0, x1);
                const float r0 = x0 - __uint_as_float(__float_as_uint(x0) & 0xFFFF0000u);
                const float r1 = x1 - __uint_as_float(__float_as_uint(x1) & 0xFFFF0000u);
                L.w4[i] = pack_trunc(r0, r1);
            }
            qhi[d0] = H.v; qlo[d0] = L.v;
        }
    }

    f32x4 Oacc[8] = {};
    float mrow[4], lrow[4];
    #pragma unroll
    for (int r = 0; r < 4; ++r) { mrow[r] = -INFINITY; lrow[r] = 0.f; }

    const int rbase = q0 + w * 16 + quad * 4;
    unsigned short* pw = sP + w * (16 * 40);

    for (int kt = 0; kt < NITER; ++kt) {
        const int k0 = kt * BK;
        __syncthreads();   // all reads of previous tile done

        // ---- DMA stage tile kt (no VGPR round-trip, no conversion) ----
        const unsigned short* Kt = Kc + (((size_t)bh * NITER + kt) << 13);
        const unsigned short* Vtt = Vt + (((size_t)bh * NITER + kt) << 12);
        #pragma unroll
        for (int i = 0; i < 4; ++i)
            GLOAD16(Kt + (w * 4 + i) * 512 + lane * 8, &sK[(w * 4 + i) * 512]);
        #pragma unroll
        for (int i = 0; i < 2; ++i)
            GLOAD16(Vtt + (w * 2 + i) * 512 + lane * 8, &sVt[(w * 2 + i) * 512]);

        // ---- SF prefetch into regs (drained by the barrier's vmcnt(0)) ----
        float sc0[4], sc1[4];
        #pragma unroll
        for (int r = 0; r < 4; ++r) {
            const float* sfr = SF + (size_t)(rbase + r) * S_LEN + k0;
            sc0[r] = sfr[lr] * LOG2E;
            sc1[r] = sfr[16 + lr] * LOG2E;
        }

        __syncthreads();   // tile staged

        // ---- QK^T, hi/lo compensated (3 passes) ----
        f32x4 acc[2] = {};
        #pragma unroll
        for (int nt = 0; nt < 2; ++nt) {
            const unsigned short* rowp = sK + (nt * 16 + lr) * 256;
            #pragma unroll
            for (int d0 = 0; d0 < 4; ++d0) {
                const int uh = (8 * d0 + 2 * quad) ^ rl;
                const s16x8 kh8 = *(const s16x8*)(rowp + (uh << 3));
                const s16x8 kl8 = *(const s16x8*)(rowp + ((uh ^ 1) << 3));
                acc[nt] = __builtin_amdgcn_mfma_f32_16x16x32_bf16(qlo[d0], kh8, acc[nt], 0, 0, 0);
                acc[nt] = __builtin_amdgcn_mfma_f32_16x16x32_bf16(qhi[d0], kl8, acc[nt], 0, 0, 0);
                acc[nt] = __builtin_amdgcn_mfma_f32_16x16x32_bf16(qhi[d0], kh8, acc[nt], 0, 0, 0);
            }
        }

        // ---- online softmax (base-2). C elem r of acc[nt]: row quad*4+r, col nt*16+lr ----
        float al[4], p0a[4], p1a[4];
        #pragma unroll
        for (int r = 0; r < 4; ++r) {
            const float t0 = acc[0][r] * sc0[r];
            const float t1 = acc[1][r] * sc1[r];
            float mx = fmaxf(t0, t1);
            mx = fmaxf(mx, __shfl_xor(mx, 1));
            mx = fmaxf(mx, __shfl_xor(mx, 2));
            mx = fmaxf(mx, __shfl_xor(mx, 4));
            mx = fmaxf(mx, __shfl_xor(mx, 8));
            const float mnew = fmaxf(mrow[r], mx);
            al[r] = EXP2(mrow[r] - mnew);
            mrow[r] = mnew;
            const float p0 = EXP2(t0 - mnew);
            const float p1 = EXP2(t1 - mnew);
            p0a[r] = p0; p1a[r] = p1;
            float rs = p0 + p1;
            rs += __shfl_xor(rs, 1);
            rs += __shfl_xor(rs, 2);
            rs += __shfl_xor(rs, 4);
            rs += __shfl_xor(rs, 8);
            lrow[r] = lrow[r] * al[r] + rs;
        }
        const f32x4 alv = {al[0], al[1], al[2], al[3]};
        #pragma unroll
        for (int dt = 0; dt < 8; ++dt)
            Oacc[dt] *= alv;
        #pragma unroll
        for (int r = 0; r < 4; ++r) {
            const int prow = quad * 4 + r;
            pw[prow * 40 + lr]      = (unsigned short)((__float_as_uint(p0a[r]) + 0x8000u) >> 16);
            pw[prow * 40 + 16 + lr] = (unsigned short)((__float_as_uint(p1a[r]) + 0x8000u) >> 16);
        }

        // ---- P·V (wave-private LDS round-trip; same-wave lgkm dependency only) ----
        const s16x8 pa = *(const s16x8*)(pw + lr * 40 + quad * 8);
        #pragma unroll
        for (int dt = 0; dt < 8; ++dt) {
            const s16x8 bv = *(const s16x8*)(sVt + (dt * 16 + lr) * 32 + quad * 8);
            Oacc[dt] = __builtin_amdgcn_mfma_f32_16x16x32_bf16(pa, bv, Oacc[dt], 0, 0, 0);
        }
    }

    // ---- epilogue ----
    const float dpf = (float)DP[0];
    float* ob = OUT + bh_off + (size_t)(q0 + w * 16) * D_DIM;
    #pragma unroll
    for (int r = 0; r < 4; ++r) {
        const float sc = dpf / lrow[r];
        const int row = quad * 4 + r;
        #pragma unroll
        for (int dt = 0; dt < 8; ++dt)
            ob[(size_t)row * D_DIM + dt * 16 + lr] = Oacc[dt][r] * sc;
    }
}

// ================= fallback (round-1 kernel, used if ws too small) =================
#define FKROW 264
#define FVROW 40
#define FPROW 40

__device__ __forceinline__ unsigned short f2bf_rne(float x) {
    union { float f; unsigned u; } a; a.f = x;
    unsigned r = a.u + 0x7FFFu + ((a.u >> 16) & 1u);
    return (unsigned short)(r >> 16);
}

__global__ __launch_bounds__(256, 2)
void attn_fused_v1(const float* __restrict__ Q, const float* __restrict__ K,
                   const float* __restrict__ V, const float* __restrict__ SF,
                   const int* __restrict__ DP, float* __restrict__ OUT)
{
    __shared__ __align__(16) unsigned short sK[32 * FKROW];
    __shared__ __align__(16) unsigned short sVt[D_DIM * FVROW];
    __shared__ __align__(16) unsigned short sP[4 * 32 * FPROW];

    const int bh = blockIdx.y, q0 = blockIdx.x * 128, tid = threadIdx.x;
    const int w = tid >> 6, lane = tid & 63, quad = lane >> 4, lr = lane & 15;
    const size_t bh_off = (size_t)bh * S_LEN * D_DIM;
    const float LOG2E = 1.4426950408889634f;

    s16x8 qhi[2][4], qlo[2][4];
    #pragma unroll
    for (int mt = 0; mt < 2; ++mt) {
        const int row = q0 + w * 32 + mt * 16 + lr;
        const float* qr = Q + bh_off + (size_t)row * D_DIM + quad * 8;
        #pragma unroll
        for (int d0 = 0; d0 < 4; ++d0) {
            const float4 u0 = *(const float4*)(qr + d0 * 32);
            const float4 u1 = *(const float4*)(qr + d0 * 32 + 4);
            float xs[8] = {u0.x,u0.y,u0.z,u0.w,u1.x,u1.y,u1.z,u1.w};
            union { s16x8 v; unsigned short u[8]; } H, L;
            #pragma unroll
            for (int j = 0; j < 8; ++j) {
                union { float f; unsigned u; } b; b.f = xs[j];
                const unsigned hb = b.u & 0xFFFF0000u;
                H.u[j] = (unsigned short)(hb >> 16);
                union { unsigned u; float f; } hf; hf.u = hb;
                L.u[j] = f2bf_rne(xs[j] - hf.f);
            }
            qhi[mt][d0] = H.v; qlo[mt][d0] = L.v;
        }
    }
    f32x4 Oacc[2][8] = {};
    float mrow[2][4], lrow[2][4];
    #pragma unroll
    for (int mt = 0; mt < 2; ++mt)
        #pragma unroll
        for (int r = 0; r < 4; ++r) { mrow[mt][r] = -INFINITY; lrow[mt][r] = 0.f; }

    for (int kt = 0; kt < NITER; ++kt) {
        const int k0 = kt * BK;
        __syncthreads();
        {
            const int r = tid >> 3, seg = tid & 7;
            const float* kr = K + bh_off + (size_t)(k0 + r) * D_DIM + seg * 16;
            unsigned short* dst = sK + r * FKROW + seg * 32;
            float xs[16];
            const float4 a0 = *(const float4*)(kr + 0);
            const float4 a1 = *(const float4*)(kr + 4);
            const float4 a2 = *(const float4*)(kr + 8);
            const float4 a3 = *(const float4*)(kr + 12);
            xs[0]=a0.x; xs[1]=a0.y; xs[2]=a0.z; xs[3]=a0.w;
            xs[4]=a1.x; xs[5]=a1.y; xs[6]=a1.z; xs[7]=a1.w;
            xs[8]=a2.x; xs[9]=a2.y; xs[10]=a2.z; xs[11]=a2.w;
            xs[12]=a3.x; xs[13]=a3.y; xs[14]=a3.z; xs[15]=a3.w;
            union { s16x8 v; unsigned short u[8]; } h0, l0, h1, l1;
            #pragma unroll
            for (int j = 0; j < 8; ++j) {
                union { float f; unsigned u; } b; b.f = xs[j];
                const unsigned hb = b.u & 0xFFFF0000u;
                h0.u[j] = (unsigned short)(hb >> 16);
                union { unsigned u; float f; } hf; hf.u = hb;
                l0.u[j] = f2bf_rne(xs[j] - hf.f);
            }
            #pragma unroll
            for (int j = 0; j < 8; ++j) {
                union { float f; unsigned u; } b; b.f = xs[8+j];
                const unsigned hb = b.u & 0xFFFF0000u;
                h1.u[j] = (unsigned short)(hb >> 16);
                union { unsigned u; float f; } hf; hf.u = hb;
                l1.u[j] = f2bf_rne(xs[8+j] - hf.f);
            }
            *(s16x8*)(dst + 0)  = h0.v;
            *(s16x8*)(dst + 8)  = l0.v;
            *(s16x8*)(dst + 16) = h1.v;
            *(s16x8*)(dst + 24) = l1.v;
        }
        {
            const int c = tid & 127, half = tid >> 7;
            const float* vb = V + bh_off + (size_t)(k0 + half * 16) * D_DIM + c;
            unsigned short* dst = sVt + c * FVROW + half * 16;
            #pragma unroll
            for (int rg = 0; rg < 4; ++rg) {
                u16x4 pk;
                pk[0] = f2bf_rne(vb[(rg*4+0) * D_DIM]);
                pk[1] = f2bf_rne(vb[(rg*4+1) * D_DIM]);
                pk[2] = f2bf_rne(vb[(rg*4+2) * D_DIM]);
                pk[3] = f2bf_rne(vb[(rg*4+3) * D_DIM]);
                *(u16x4*)(dst + rg * 4) = pk;
            }
        }
        __syncthreads();
        f32x4 acc[2][2] = {};
        #pragma unroll
        for (int nt = 0; nt < 2; ++nt) {
            #pragma unroll
            for (int d0 = 0; d0 < 4; ++d0) {
                const unsigned short* src = sK + (nt*16 + lr) * FKROW + (d0*4 + quad) * 16;
                const s16x8 bh8 = *(const s16x8*)(src);
                const s16x8 bl8 = *(const s16x8*)(src + 8);
                #pragma unroll
                for (int mt = 0; mt < 2; ++mt) {
                    acc[mt][nt] = __builtin_amdgcn_mfma_f32_16x16x32_bf16(qlo[mt][d0], bh8, acc[mt][nt], 0, 0, 0);
                    acc[mt][nt] = __builtin_amdgcn_mfma_f32_16x16x32_bf16(qhi[mt][d0], bl8, acc[mt][nt], 0, 0, 0);
                    acc[mt][nt] = __builtin_amdgcn_mfma_f32_16x16x32_bf16(qhi[mt][d0], bh8, acc[mt][nt], 0, 0, 0);
                }
            }
        }
        unsigned short* pw = sP + w * (32 * FPROW);
        #pragma unroll
        for (int mt = 0; mt < 2; ++mt) {
            const int rbase = q0 + w * 32 + mt * 16 + quad * 4;
            float t0[4], t1[4];
            #pragma unroll
            for (int r = 0; r < 4; ++r) {
                const float s0 = SF[(size_t)(rbase + r) * S_LEN + k0 + lr];
                const float s1 = SF[(size_t)(rbase + r) * S_LEN + k0 + 16 + lr];
                t0[r] = acc[mt][0][r] * s0 * LOG2E;
                t1[r] = acc[mt][1][r] * s1 * LOG2E;
            }
            #pragma unroll
            for (int r = 0; r < 4; ++r) {
                float mx = fmaxf(t0[r], t1[r]);
                mx = fmaxf(mx, __shfl_xor(mx, 1));
                mx = fmaxf(mx, __shfl_xor(mx, 2));
                mx = fmaxf(mx, __shfl_xor(mx, 4));
                mx = fmaxf(mx, __shfl_xor(mx, 8));
                const float mnew = fmaxf(mrow[mt][r], mx);
                const float a2 = EXP2(mrow[mt][r] - mnew);
                mrow[mt][r] = mnew;
                const float p0 = EXP2(t0[r] - mnew);
                const float p1 = EXP2(t1[r] - mnew);
                float rs = p0 + p1;
                rs += __shfl_xor(rs, 1);
                rs += __shfl_xor(rs, 2);
                rs += __shfl_xor(rs, 4);
                rs += __shfl_xor(rs, 8);
                lrow[mt][r] = lrow[mt][r] * a2 + rs;
                #pragma unroll
                for (int dt = 0; dt < 8; ++dt)
                    Oacc[mt][dt][r] *= a2;
                const int prow = mt * 16 + quad * 4 + r;
                pw[prow * FPROW + lr]      = f2bf_rne(p0);
                pw[prow * FPROW + 16 + lr] = f2bf_rne(p1);
            }
        }
        s16x8 pa[2];
        pa[0] = *(const s16x8*)(pw + (0*16 + lr) * FPROW + quad * 8);
        pa[1] = *(const s16x8*)(pw + (1*16 + lr) * FPROW + quad * 8);
        #pragma unroll
        for (int dt = 0; dt < 8; ++dt) {
            const s16x8 bv = *(const s16x8*)(sVt + (dt*16 + lr) * FVROW + quad * 8);
            Oacc[0][dt] = __builtin_amdgcn_mfma_f32_16x16x32_bf16(pa[0], bv, Oacc[0][dt], 0, 0, 0);
            Oacc[1][dt] = __builtin_amdgcn_mfma_f32_16x16x32_bf16(pa[1], bv, Oacc[1][dt], 0, 0, 0);
        }
    }
    const float dpf = (float)DP[0];
    float* ob = OUT + bh_off + (size_t)(q0 + w * 32) * D_DIM;
    #pragma unroll
    for (int mt = 0; mt < 2; ++mt) {
        #pragma unroll
        for (int r = 0; r < 4; ++r) {
            const float sc = dpf / lrow[mt][r];
            const int row = mt * 16 + quad * 4 + r;
            #pragma unroll
            for (int dt = 0; dt < 8; ++dt)
                ob[(size_t)row * D_DIM + dt * 16 + lr] = Oacc[mt][dt][r] * sc;
        }
    }
}

extern "C" void kernel_launch(void* const* d_in, const int* in_sizes, int n_in,
                              void* d_out, int out_size, void* d_ws, size_t ws_size,
                              hipStream_t stream) {
    const float* q  = (const float*)d_in[0];
    const float* k  = (const float*)d_in[1];
    const float* v  = (const float*)d_in[2];
    const float* sf = (const float*)d_in[3];
    const int*   dp = (const int*)d_in[4];
    float* out = (float*)d_out;

    const size_t kc_ushorts = (size_t)32 * NITER * 32 * 256;   // 33.55 MB
    const size_t vt_ushorts = (size_t)32 * NITER * D_DIM * 32; // 16.78 MB
    const size_t need = (kc_ushorts + vt_ushorts) * 2;

    if (ws_size >= need) {
        unsigned short* Kc = (unsigned short*)d_ws;
        unsigned short* Vt = Kc + kc_ushorts;
        prep_k<<<4096, 256, 0, stream>>>(k, Kc);
        prep_v<<<1024, 256, 0, stream>>>(v, Vt);
        dim3 grid(S_LEN / BQ, 32);   // (32, 32) = 1024 blocks, 4/CU
        attn_fused<<<grid, dim3(256), 0, stream>>>(q, Kc, Vt, sf, dp, out);
    } else {
        dim3 grid(S_LEN / 128, 32);
        attn_fused_v1<<<grid, dim3(256), 0, stream>>>(q, k, v, sf, dp, out);
    }
}

// Round 3
// 427.212 us; speedup vs baseline: 1.6277x; 1.0870x over previous
//
#include <hip/hip_runtime.h>

#define S_LEN 2048
#define D_DIM 128
#define BQ 64
#define BK 32
#define NITER (S_LEN / BK)   // 64

typedef float f32x4 __attribute__((ext_vector_type(4)));
typedef short s16x8 __attribute__((ext_vector_type(8)));
typedef unsigned int u32;

#if __has_builtin(__builtin_amdgcn_exp2f)
#define EXP2(x) __builtin_amdgcn_exp2f(x)
#else
#define EXP2(x) exp2f(x)
#endif

// pack two floats' bf16 (truncated) into one u32: x1 in upper 16, x0 in lower
__device__ __forceinline__ u32 pack_trunc(float x0, float x1) {
    return __builtin_amdgcn_perm(__float_as_uint(x1), __float_as_uint(x0), 0x07060302u);
}
// round-to-nearest bf16 pack
__device__ __forceinline__ u32 pack_rne(float x0, float x1) {
    return __builtin_amdgcn_perm(__float_as_uint(x1) + 0x8000u,
                                 __float_as_uint(x0) + 0x8000u, 0x07060302u);
}

#define GLOAD16(g, l) \
    __builtin_amdgcn_global_load_lds((const __attribute__((address_space(1))) u32*)(g), \
                                     (__attribute__((address_space(3))) u32*)(l), 16, 0, 0)

// ---- DPP 16-lane row reductions (VALU pipe, no LDS) ----
// xor1 = quad_perm(1,0,3,2)=0xB1; xor2 = quad_perm(2,3,0,1)=0x4E;
// xor7 = row_half_mirror=0x141;   xor15 = row_mirror=0x140.
template <int CTRL>
__device__ __forceinline__ float dppmov(float x) {
    return __int_as_float(__builtin_amdgcn_update_dpp(0, __float_as_int(x), CTRL, 0xF, 0xF, true));
}
__device__ __forceinline__ float row_max16(float x) {
    x = fmaxf(x, dppmov<0xB1>(x));
    x = fmaxf(x, dppmov<0x4E>(x));
    x = fmaxf(x, dppmov<0x141>(x));
    x = fmaxf(x, dppmov<0x140>(x));
    return x;
}
__device__ __forceinline__ float row_sum16(float x) {
    x += dppmov<0xB1>(x);
    x += dppmov<0x4E>(x);
    x += dppmov<0x141>(x);
    x += dppmov<0x140>(x);
    return x;
}

// ---------------- pre-pass: K -> hi/lo bf16, tiled + XOR-swizzled 16B units ----------------
// Kc layout: [bh][kt][r=0..31][u'=0..31][8 ushorts]; u = 2c (hi) / 2c+1 (lo); u' = u ^ (r&7).
__global__ void prep_k(const float* __restrict__ K, unsigned short* __restrict__ Kc) {
    const int t  = blockIdx.x * 256 + threadIdx.x;   // 2^20 threads
    const int c  = t & 15;
    const int s  = (t >> 4) & (S_LEN - 1);
    const int bh = t >> 15;
    const float* src = K + ((size_t)bh * S_LEN + s) * D_DIM + c * 8;
    const float4 a = *(const float4*)src;
    const float4 b = *(const float4*)(src + 4);
    const float x[8] = {a.x,a.y,a.z,a.w,b.x,b.y,b.z,b.w};
    u32 h[4], l[4];
    #pragma unroll
    for (int i = 0; i < 4; ++i) {
        const float x0 = x[2*i], x1 = x[2*i+1];
        h[i] = pack_trunc(x0, x1);
        const float r0 = x0 - __uint_as_float(__float_as_uint(x0) & 0xFFFF0000u);
        const float r1 = x1 - __uint_as_float(__float_as_uint(x1) & 0xFFFF0000u);
        l[i] = pack_trunc(r0, r1);
    }
    const int kt = s >> 5, r = s & 31, rl = r & 7;
    unsigned short* base = Kc + ((((size_t)bh * NITER + kt) * 32 + r) << 8);
    *(uint4*)(base + (((2*c)     ^ rl) << 3)) = make_uint4(h[0],h[1],h[2],h[3]);
    *(uint4*)(base + (((2*c + 1) ^ rl) << 3)) = make_uint4(l[0],l[1],l[2],l[3]);
}

// ---------------- pre-pass: V -> transposed bf16 tiles Vt[bh][kt][d][kk] ----------------
__global__ void prep_v(const float* __restrict__ V, unsigned short* __restrict__ Vt) {
    const int t  = blockIdx.x * 256 + threadIdx.x;   // 2^18 threads
    const int d  = t & 127;
    const int kt = (t >> 7) & (NITER - 1);
    const int bh = t >> 13;
    const float* src = V + (((size_t)bh * NITER + kt) * BK) * D_DIM + d;
    u32 wv[16];
    #pragma unroll
    for (int i = 0; i < 16; ++i)
        wv[i] = pack_rne(src[(2*i) * D_DIM], src[(2*i+1) * D_DIM]);
    unsigned short* dst = Vt + ((((size_t)bh * NITER + kt) * D_DIM + d) << 5);
    #pragma unroll
    for (int i = 0; i < 4; ++i)
        *(uint4*)(dst + i * 8) = make_uint4(wv[4*i],wv[4*i+1],wv[4*i+2],wv[4*i+3]);
}

// ---------------- hot kernel: dbuf single-barrier K-loop ----------------
__global__ __launch_bounds__(256, 3)
void attn_fused(const float* __restrict__ Q, const unsigned short* __restrict__ Kc,
                const unsigned short* __restrict__ Vt, const float* __restrict__ SF,
                const int* __restrict__ DP, float* __restrict__ OUT)
{
    __shared__ __align__(16) unsigned short sK[2][32 * 256];    // 2 x 16 KB
    __shared__ __align__(16) unsigned short sVt[2][128 * 32];   // 2 x 8 KB
    __shared__ __align__(16) unsigned short sP[4 * 16 * 32];    // 4 KB, wave-private

    const int bh   = blockIdx.y;
    const int q0   = blockIdx.x * BQ;
    const int tid  = threadIdx.x;
    const int w    = tid >> 6;
    const int lane = tid & 63;
    const int quad = lane >> 4;
    const int lr   = lane & 15;
    const int rl   = lr & 7;

    const size_t bh_off = (size_t)bh * S_LEN * D_DIM;
    const float LOG2E = 1.4426950408889634f;

    // ---- Q fragments, hi/lo bf16 split (A-frag: lane holds A[m=lr][k=quad*8+j]) ----
    s16x8 qhi[4], qlo[4];
    {
        const int qrow = q0 + w * 16 + lr;
        const float* qr = Q + bh_off + (size_t)qrow * D_DIM + quad * 8;
        #pragma unroll
        for (int d0 = 0; d0 < 4; ++d0) {
            const float4 u0 = *(const float4*)(qr + d0 * 32);
            const float4 u1 = *(const float4*)(qr + d0 * 32 + 4);
            const float x[8] = {u0.x,u0.y,u0.z,u0.w,u1.x,u1.y,u1.z,u1.w};
            union { u32 w4[4]; s16x8 v; } H, L;
            #pragma unroll
            for (int i = 0; i < 4; ++i) {
                const float x0 = x[2*i], x1 = x[2*i+1];
                H.w4[i] = pack_trunc(x0, x1);
                const float r0 = x0 - __uint_as_float(__float_as_uint(x0) & 0xFFFF0000u);
                const float r1 = x1 - __uint_as_float(__float_as_uint(x1) & 0xFFFF0000u);
                L.w4[i] = pack_trunc(r0, r1);
            }
            qhi[d0] = H.v; qlo[d0] = L.v;
        }
    }

    f32x4 Oacc[8] = {};
    float mrow[4], lrow[4];
    #pragma unroll
    for (int r = 0; r < 4; ++r) { mrow[r] = -INFINITY; lrow[r] = 0.f; }

    const int rbase = q0 + w * 16 + quad * 4;
    unsigned short* pw = sP + w * (16 * 32);

    const unsigned short* KtBase = Kc + (((size_t)bh * NITER) << 13);
    const unsigned short* VtBase = Vt + (((size_t)bh * NITER) << 12);

    // ---- prologue: DMA tile 0 -> buf 0; SF tile 0 -> regs ----
    #pragma unroll
    for (int i = 0; i < 4; ++i)
        GLOAD16(KtBase + (w * 4 + i) * 512 + lane * 8, &sK[0][(w * 4 + i) * 512]);
    #pragma unroll
    for (int i = 0; i < 2; ++i)
        GLOAD16(VtBase + (w * 2 + i) * 512 + lane * 8, &sVt[0][(w * 2 + i) * 512]);

    float sc0[4], sc1[4];
    #pragma unroll
    for (int r = 0; r < 4; ++r) {
        const float* sfr = SF + (size_t)(rbase + r) * S_LEN;
        sc0[r] = sfr[lr] * LOG2E;
        sc1[r] = sfr[16 + lr] * LOG2E;
    }

    for (int kt = 0; kt < NITER; ++kt) {
        const int p = kt & 1;
        // Publishes buf[p] (vmcnt(0) drain: its DMA was issued a full iteration
        // ago). Also guarantees everyone is done reading buf[1-p] before we
        // overwrite it below.
        __syncthreads();

        // ---- prefetch tile kt+1 into buf[1-p]; SF(kt+1) into regs ----
        float n0[4], n1[4];
        const bool more = (kt + 1 < NITER);
        if (more) {
            const unsigned short* Kn = KtBase + ((size_t)(kt + 1) << 13);
            const unsigned short* Vn = VtBase + ((size_t)(kt + 1) << 12);
            #pragma unroll
            for (int i = 0; i < 4; ++i)
                GLOAD16(Kn + (w * 4 + i) * 512 + lane * 8, &sK[1 - p][(w * 4 + i) * 512]);
            #pragma unroll
            for (int i = 0; i < 2; ++i)
                GLOAD16(Vn + (w * 2 + i) * 512 + lane * 8, &sVt[1 - p][(w * 2 + i) * 512]);
            #pragma unroll
            for (int r = 0; r < 4; ++r) {
                const float* sfr = SF + (size_t)(rbase + r) * S_LEN + (kt + 1) * BK;
                n0[r] = sfr[lr] * LOG2E;
                n1[r] = sfr[16 + lr] * LOG2E;
            }
        }

        // ---- QK^T on buf[p], hi/lo compensated (3 passes) ----
        const unsigned short* sKp = sK[p];
        f32x4 acc[2] = {};
        #pragma unroll
        for (int nt = 0; nt < 2; ++nt) {
            const unsigned short* rowp = sKp + (nt * 16 + lr) * 256;
            #pragma unroll
            for (int d0 = 0; d0 < 4; ++d0) {
                const int uh = (8 * d0 + 2 * quad) ^ rl;
                const s16x8 kh8 = *(const s16x8*)(rowp + (uh << 3));
                const s16x8 kl8 = *(const s16x8*)(rowp + ((uh ^ 1) << 3));
                acc[nt] = __builtin_amdgcn_mfma_f32_16x16x32_bf16(qlo[d0], kh8, acc[nt], 0, 0, 0);
                acc[nt] = __builtin_amdgcn_mfma_f32_16x16x32_bf16(qhi[d0], kl8, acc[nt], 0, 0, 0);
                acc[nt] = __builtin_amdgcn_mfma_f32_16x16x32_bf16(qhi[d0], kh8, acc[nt], 0, 0, 0);
            }
        }

        // ---- online softmax (base-2), DPP reductions ----
        float al[4], p0a[4], p1a[4];
        #pragma unroll
        for (int r = 0; r < 4; ++r) {
            const float t0 = acc[0][r] * sc0[r];
            const float t1 = acc[1][r] * sc1[r];
            const float mx = row_max16(fmaxf(t0, t1));
            const float mnew = fmaxf(mrow[r], mx);
            al[r] = EXP2(mrow[r] - mnew);
            mrow[r] = mnew;
            const float p0 = EXP2(t0 - mnew);
            const float p1 = EXP2(t1 - mnew);
            p0a[r] = p0; p1a[r] = p1;
            const float rs = row_sum16(p0 + p1);
            lrow[r] = lrow[r] * al[r] + rs;
        }
        const f32x4 alv = {al[0], al[1], al[2], al[3]};
        #pragma unroll
        for (int dt = 0; dt < 8; ++dt)
            Oacc[dt] *= alv;
        #pragma unroll
        for (int r = 0; r < 4; ++r) {
            const int prow = quad * 4 + r;
            pw[prow * 32 + lr]      = (unsigned short)((__float_as_uint(p0a[r]) + 0x8000u) >> 16);
            pw[prow * 32 + 16 + lr] = (unsigned short)((__float_as_uint(p1a[r]) + 0x8000u) >> 16);
        }

        // ---- P·V on buf[p] (wave-private LDS round-trip, same-wave lgkm dep) ----
        const s16x8 pa = *(const s16x8*)(pw + lr * 32 + quad * 8);
        const unsigned short* sVp = sVt[p];
        #pragma unroll
        for (int dt = 0; dt < 8; ++dt) {
            const s16x8 bv = *(const s16x8*)(sVp + (dt * 16 + lr) * 32 + quad * 8);
            Oacc[dt] = __builtin_amdgcn_mfma_f32_16x16x32_bf16(pa, bv, Oacc[dt], 0, 0, 0);
        }

        if (more) {
            #pragma unroll
            for (int r = 0; r < 4; ++r) { sc0[r] = n0[r]; sc1[r] = n1[r]; }
        }
    }

    // ---- epilogue ----
    const float dpf = (float)DP[0];
    float* ob = OUT + bh_off + (size_t)(q0 + w * 16) * D_DIM;
    #pragma unroll
    for (int r = 0; r < 4; ++r) {
        const float sc = dpf / lrow[r];
        const int row = quad * 4 + r;
        #pragma unroll
        for (int dt = 0; dt < 8; ++dt)
            ob[(size_t)row * D_DIM + dt * 16 + lr] = Oacc[dt][r] * sc;
    }
}

extern "C" void kernel_launch(void* const* d_in, const int* in_sizes, int n_in,
                              void* d_out, int out_size, void* d_ws, size_t ws_size,
                              hipStream_t stream) {
    const float* q  = (const float*)d_in[0];
    const float* k  = (const float*)d_in[1];
    const float* v  = (const float*)d_in[2];
    const float* sf = (const float*)d_in[3];
    const int*   dp = (const int*)d_in[4];
    float* out = (float*)d_out;

    const size_t kc_ushorts = (size_t)32 * NITER * 32 * 256;   // 33.55 M elems
    unsigned short* Kc = (unsigned short*)d_ws;
    unsigned short* Vt = Kc + kc_ushorts;

    prep_k<<<4096, 256, 0, stream>>>(k, Kc);
    prep_v<<<1024, 256, 0, stream>>>(v, Vt);
    dim3 grid(S_LEN / BQ, 32);   // (32, 32) = 1024 blocks
    attn_fused<<<grid, dim3(256), 0, stream>>>(q, Kc, Vt, sf, dp, out);
}